// Round 13
// baseline (4726.208 us; speedup 1.0000x reference)
//
#include <hip/hip_runtime.h>

#define NN 50000
#define FF 24
#define HH 128
#define TT 12
#define EE 800000
#define HORZ 6

// ---------------- mask dtype detection + canonicalization ----------------

__global__ void k_maskdetect(const unsigned char* __restrict__ m, int* __restrict__ flag) {
    int i = blockIdx.x * 256 + threadIdx.x;
    if (i < 16384 && (i & 3) != 0 && m[i] != 0) atomicOr(flag, 1);
}

__global__ void k_maskconv(const unsigned char* __restrict__ mraw, const int* __restrict__ flag,
                           unsigned char* __restrict__ mout) {
    int i = blockIdx.x * 256 + threadIdx.x;
    if (i >= TT * NN) return;
    if (*flag) mout[i] = (mraw[i] != 0);
    else       mout[i] = (((const int*)mraw)[i] != 0);
}

// ---------------- CSR build: histogram(+rank) -> scan -> rank-based fill ----------------

__global__ void k_hist(const int* __restrict__ ei, int* __restrict__ cnt,
                       int* __restrict__ rank) {
    int idx = blockIdx.x * 256 + threadIdx.x;          // over T*E
    if (idx >= TT * EE) return;
    int t = idx / EE, e = idx - t * EE;
    int dst = ei[((size_t)t * 2 + 1) * EE + e];
    rank[idx] = atomicAdd(&cnt[t * NN + dst], 1);      // rank within dst row
}

__global__ void k_scan(const int* __restrict__ cnt, int* __restrict__ offs) {
    __shared__ int sums[1024];
    int t = blockIdx.x, tid = threadIdx.x;
    const int per = (NN + 1023) / 1024;                // 49
    int base = tid * per;
    int s = 0;
    for (int i = 0; i < per; i++) {
        int idx = base + i;
        if (idx < NN) s += cnt[t * NN + idx];
    }
    sums[tid] = s;
    __syncthreads();
    for (int off = 1; off < 1024; off <<= 1) {
        int tv = (tid >= off) ? sums[tid - off] : 0;
        __syncthreads();
        sums[tid] += tv;
        __syncthreads();
    }
    int run = sums[tid] - s;                           // exclusive prefix
    for (int i = 0; i < per; i++) {
        int idx = base + i;
        if (idx < NN) {
            offs[t * (NN + 1) + idx] = run;
            run += cnt[t * NN + idx];
        }
    }
    if (tid == 1023) offs[t * (NN + 1) + NN] = sums[1023];
}

// atomic-free fill: pos = offs[dst] + rank[e]; interleaved (src,ea) 8B fire-and-forget stores.
__global__ void k_fill(const int* __restrict__ ei, const float* __restrict__ ea,
                       const int* __restrict__ offs, const int* __restrict__ rank,
                       int2* __restrict__ edges) {
    int idx = blockIdx.x * 256 + threadIdx.x;          // over T*E
    if (idx >= TT * EE) return;
    int t = idx / EE, e = idx - t * EE;
    int dst = ei[((size_t)t * 2 + 1) * EE + e];
    int src = ei[((size_t)t * 2 + 0) * EE + e];
    int pos = offs[t * (NN + 1) + dst] + rank[idx];
    edges[(size_t)t * EE + pos] = make_int2(src, __float_as_int(ea[(size_t)t * EE + e]));
}

// deg[n] = sum of incoming ea; dinv = rsqrt(deg+1)
__global__ void k_degdinv(const int* __restrict__ offs, const int2* __restrict__ edges,
                          float* __restrict__ dinv) {
    int idx = blockIdx.x * 256 + threadIdx.x;          // over T*N
    if (idx >= TT * NN) return;
    int t = idx / NN, n = idx - t * NN;
    int b = offs[t * (NN + 1) + n], en = offs[t * (NN + 1) + n + 1];
    float s = 0.f;
    for (int j = b; j < en; j++) s += __int_as_float(edges[(size_t)t * EE + j].y);
    dinv[idx] = rsqrtf(s + 1.0f);
}

// edge coefficient: ea *= dinv[src]*dinv[dst]
__global__ void k_coef(const int* __restrict__ offs, const float* __restrict__ dinv,
                       int2* __restrict__ edges) {
    int idx = blockIdx.x * 256 + threadIdx.x;          // over T*N
    if (idx >= TT * NN) return;
    int t = idx / NN, n = idx - t * NN;
    int b = offs[t * (NN + 1) + n], en = offs[t * (NN + 1) + n + 1];
    float di = dinv[idx];
    for (int j = b; j < en; j++) {
        int2 p = edges[(size_t)t * EE + j];
        float v = __int_as_float(p.y) * di * dinv[t * NN + p.x];
        edges[(size_t)t * EE + j].y = __float_as_int(v);
    }
}

// ---------------- weight folding: Cg = Wg @ LWg[0:H], b2g = bg @ LWg[0:H] + Lbg ----------------

__global__ void k_fold(const float* __restrict__ Wz, const float* __restrict__ Wr,
                       const float* __restrict__ Wh,
                       const float* __restrict__ bz, const float* __restrict__ br,
                       const float* __restrict__ bh,
                       const float* __restrict__ LWz, const float* __restrict__ LWr,
                       const float* __restrict__ LWh,
                       const float* __restrict__ Lbz, const float* __restrict__ Lbr,
                       const float* __restrict__ Lbh,
                       float* __restrict__ Call, float* __restrict__ b2) {
    int g = blockIdx.x, c = threadIdx.x;               // 3 blocks x 128
    const float* W  = g == 0 ? Wz : (g == 1 ? Wr : Wh);
    const float* LW = g == 0 ? LWz : (g == 1 ? LWr : LWh);
    const float* bg = g == 0 ? bz : (g == 1 ? br : bh);
    const float* Lb = g == 0 ? Lbz : (g == 1 ? Lbr : Lbh);
    for (int j = 0; j < FF; j++) {
        float a = 0.f;
        for (int k = 0; k < HH; k++) a += W[j * HH + k] * LW[k * HH + c];
        Call[((size_t)g * FF + j) * HH + c] = a;
    }
    float a = Lb[c];
    for (int k = 0; k < HH; k++) a += bg[k] * LW[k * HH + c];
    b2[g * HH + c] = a;
}

// ---------------- gather body (shared): 6 threads/node, float4 payload, int2 edge meta ----------

__device__ __forceinline__ void gather_body(int n, int q, const float* __restrict__ x,
                                            const int* __restrict__ offs,
                                            const int2* __restrict__ edges,
                                            const float* __restrict__ dinv,
                                            float* __restrict__ xe) {
    int b = offs[n], en = offs[n + 1];
    float di = dinv[n];
    float sc = di * di;
    float4 acc = *(const float4*)&x[(size_t)n * FF + q * 4];
    acc.x *= sc; acc.y *= sc; acc.z *= sc; acc.w *= sc;
    for (int j = b; j < en; j++) {
        int2 p = edges[j];
        float w = __int_as_float(p.y);
        float4 v = *(const float4*)&x[(size_t)p.x * FF + q * 4];
        acc.x += v.x * w; acc.y += v.y * w; acc.z += v.z * w; acc.w += v.w * w;
    }
    *(float4*)&xe[(size_t)n * FF + q * 4] = acc;
}

// per-step gather (decoder / fallback path)
__global__ void k_gather(const float* __restrict__ x, const int* __restrict__ offs,
                         const int2* __restrict__ edges, const float* __restrict__ dinv,
                         float* __restrict__ xe) {
    int idx = blockIdx.x * 256 + threadIdx.x;          // over N*6
    if (idx >= NN * 6) return;
    int n = idx / 6, q = idx - n * 6;
    gather_body(n, q, x, offs, edges, dinv, xe);
}

// batched gather: all 12 encoder steps in one launch (input-dependent only)
__global__ void k_gather12(const float* __restrict__ x_seq, const int* __restrict__ offs_all,
                           const int2* __restrict__ edges_all, const float* __restrict__ dinv_all,
                           float* __restrict__ xe_all) {
    int idx = blockIdx.x * 256 + threadIdx.x;          // over 12*N*6
    if (idx >= TT * NN * 6) return;
    int t = idx / (NN * 6);
    int r = idx - t * (NN * 6);
    int n = r / 6, q = r - n * 6;
    gather_body(n, q,
                x_seq + (size_t)t * NN * FF,
                offs_all + t * (NN + 1),
                edges_all + (size_t)t * EE,
                dinv_all + t * NN,
                xe_all + (size_t)t * NN * FF);
}

// ---------------- fused GRU cell (R9 shape; z in registers, s_z removed, lb(256,5)) ----------

#define FMA8X2(SARR, M0, K)                                                                  \
    {                                                                                        \
        float4 v_;                                                                           \
        v_ = *(const float4*)&SARR[M0 + 0][K];                                               \
        az0 += v_.x*wz0 + v_.y*wz1 + v_.z*wz2 + v_.w*wz3;                                    \
        ar0 += v_.x*wr0 + v_.y*wr1 + v_.z*wr2 + v_.w*wr3;                                    \
        v_ = *(const float4*)&SARR[M0 + 1][K];                                               \
        az1 += v_.x*wz0 + v_.y*wz1 + v_.z*wz2 + v_.w*wz3;                                    \
        ar1 += v_.x*wr0 + v_.y*wr1 + v_.z*wr2 + v_.w*wr3;                                    \
        v_ = *(const float4*)&SARR[M0 + 2][K];                                               \
        az2 += v_.x*wz0 + v_.y*wz1 + v_.z*wz2 + v_.w*wz3;                                    \
        ar2 += v_.x*wr0 + v_.y*wr1 + v_.z*wr2 + v_.w*wr3;                                    \
        v_ = *(const float4*)&SARR[M0 + 3][K];                                               \
        az3 += v_.x*wz0 + v_.y*wz1 + v_.z*wz2 + v_.w*wz3;                                    \
        ar3 += v_.x*wr0 + v_.y*wr1 + v_.z*wr2 + v_.w*wr3;                                    \
        v_ = *(const float4*)&SARR[M0 + 4][K];                                               \
        az4 += v_.x*wz0 + v_.y*wz1 + v_.z*wz2 + v_.w*wz3;                                    \
        ar4 += v_.x*wr0 + v_.y*wr1 + v_.z*wr2 + v_.w*wr3;                                    \
        v_ = *(const float4*)&SARR[M0 + 5][K];                                               \
        az5 += v_.x*wz0 + v_.y*wz1 + v_.z*wz2 + v_.w*wz3;                                    \
        ar5 += v_.x*wr0 + v_.y*wr1 + v_.z*wr2 + v_.w*wr3;                                    \
        v_ = *(const float4*)&SARR[M0 + 6][K];                                               \
        az6 += v_.x*wz0 + v_.y*wz1 + v_.z*wz2 + v_.w*wz3;                                    \
        ar6 += v_.x*wr0 + v_.y*wr1 + v_.z*wr2 + v_.w*wr3;                                    \
        v_ = *(const float4*)&SARR[M0 + 7][K];                                               \
        az7 += v_.x*wz0 + v_.y*wz1 + v_.z*wz2 + v_.w*wz3;                                    \
        ar7 += v_.x*wr0 + v_.y*wr1 + v_.z*wr2 + v_.w*wr3;                                    \
    }

#define FMA8X(SARR, M0, K)                                                        \
    {                                                                             \
        float4 v_;                                                                \
        v_ = *(const float4*)&SARR[M0 + 0][K]; a0 += v_.x*w0 + v_.y*w1 + v_.z*w2 + v_.w*w3; \
        v_ = *(const float4*)&SARR[M0 + 1][K]; a1 += v_.x*w0 + v_.y*w1 + v_.z*w2 + v_.w*w3; \
        v_ = *(const float4*)&SARR[M0 + 2][K]; a2 += v_.x*w0 + v_.y*w1 + v_.z*w2 + v_.w*w3; \
        v_ = *(const float4*)&SARR[M0 + 3][K]; a3 += v_.x*w0 + v_.y*w1 + v_.z*w2 + v_.w*w3; \
        v_ = *(const float4*)&SARR[M0 + 4][K]; a4 += v_.x*w0 + v_.y*w1 + v_.z*w2 + v_.w*w3; \
        v_ = *(const float4*)&SARR[M0 + 5][K]; a5 += v_.x*w0 + v_.y*w1 + v_.z*w2 + v_.w*w3; \
        v_ = *(const float4*)&SARR[M0 + 6][K]; a6 += v_.x*w0 + v_.y*w1 + v_.z*w2 + v_.w*w3; \
        v_ = *(const float4*)&SARR[M0 + 7][K]; a7 += v_.x*w0 + v_.y*w1 + v_.z*w2 + v_.w*w3; \
    }

template <int DOHEAD>
__global__ __launch_bounds__(256, 5) void k_cell(
        const float* __restrict__ xe, const float* __restrict__ hin,
        const unsigned char* __restrict__ gmask,
        const float* __restrict__ Call, const float* __restrict__ b2,
        const float* __restrict__ LWz, const float* __restrict__ LWr,
        const float* __restrict__ LWh,
        const unsigned char* __restrict__ wmask, float* __restrict__ hout,
        const float* __restrict__ headW, const float* __restrict__ headb,
        float* __restrict__ y) {
    __shared__ float s_xe[16][FF];
    __shared__ float s_h0[16][HH];
    __shared__ float s_hr[16][HH];
    int nb = blockIdx.x * 16;
    int tid = threadIdx.x;

    for (int i = tid; i < 16 * FF; i += 256) {
        s_xe[i / FF][i % FF] = xe[(size_t)nb * FF + i];
    }
    for (int i = tid; i < 16 * HH; i += 256) {
        int m = i >> 7, k = i & 127;
        float v = hin[((size_t)nb + m) * HH + k];
        if (gmask && !gmask[nb + m]) v = 0.f;
        s_h0[m][k] = v;
    }
    __syncthreads();

    int g = tid >> 7, c = tid & 127;
    int m0 = g * 8;                                    // row half owned by this thread

    float zz0, zz1, zz2, zz3, zz4, zz5, zz6, zz7;      // z in registers across phases

    // ---- phase A: z AND r for 8 rows x column c ----
    {
        const float* Cz   = Call;
        const float* Cr   = Call + (size_t)FF * HH;
        const float* LWzb = LWz + (size_t)HH * HH;
        const float* LWrb = LWr + (size_t)HH * HH;
        float bbz = b2[c], bbr = b2[HH + c];
        float az0 = bbz, az1 = bbz, az2 = bbz, az3 = bbz, az4 = bbz, az5 = bbz, az6 = bbz, az7 = bbz;
        float ar0 = bbr, ar1 = bbr, ar2 = bbr, ar3 = bbr, ar4 = bbr, ar5 = bbr, ar6 = bbr, ar7 = bbr;
#pragma unroll
        for (int k = 0; k < FF; k += 4) {
            float wz0 = Cz[(k + 0) * HH + c], wz1 = Cz[(k + 1) * HH + c];
            float wz2 = Cz[(k + 2) * HH + c], wz3 = Cz[(k + 3) * HH + c];
            float wr0 = Cr[(k + 0) * HH + c], wr1 = Cr[(k + 1) * HH + c];
            float wr2 = Cr[(k + 2) * HH + c], wr3 = Cr[(k + 3) * HH + c];
            FMA8X2(s_xe, m0, k);
        }
#pragma unroll 4
        for (int k = 0; k < HH; k += 4) {
            float wz0 = LWzb[(k + 0) * HH + c], wz1 = LWzb[(k + 1) * HH + c];
            float wz2 = LWzb[(k + 2) * HH + c], wz3 = LWzb[(k + 3) * HH + c];
            float wr0 = LWrb[(k + 0) * HH + c], wr1 = LWrb[(k + 1) * HH + c];
            float wr2 = LWrb[(k + 2) * HH + c], wr3 = LWrb[(k + 3) * HH + c];
            FMA8X2(s_h0, m0, k);
        }
#define PHA_EP(R, AZ, AR, ZZ)                                                    \
        ZZ = 1.f / (1.f + __expf(-(AZ)));                                        \
        s_hr[m0 + R][c] = (1.f / (1.f + __expf(-(AR)))) * s_h0[m0 + R][c];
        PHA_EP(0, az0, ar0, zz0) PHA_EP(1, az1, ar1, zz1)
        PHA_EP(2, az2, ar2, zz2) PHA_EP(3, az3, ar3, zz3)
        PHA_EP(4, az4, ar4, zz4) PHA_EP(5, az5, ar5, zz5)
        PHA_EP(6, az6, ar6, zz6) PHA_EP(7, az7, ar7, zz7)
#undef PHA_EP
    }
    __syncthreads();

    // ---- phase B: htil + GRU update; g=0 rows 0-7, g=1 rows 8-15 ----
    {
        const float* Ch   = Call + (size_t)2 * FF * HH;
        const float* LWhb = LWh + (size_t)HH * HH;
        float bb = b2[2 * HH + c];
        float a0 = bb, a1 = bb, a2 = bb, a3 = bb, a4 = bb, a5 = bb, a6 = bb, a7 = bb;
#pragma unroll
        for (int k = 0; k < FF; k += 4) {
            float w0 = Ch[(k + 0) * HH + c], w1 = Ch[(k + 1) * HH + c];
            float w2 = Ch[(k + 2) * HH + c], w3 = Ch[(k + 3) * HH + c];
            FMA8X(s_xe, m0, k);
        }
#pragma unroll 4
        for (int k = 0; k < HH; k += 4) {
            float w0 = LWhb[(k + 0) * HH + c], w1 = LWhb[(k + 1) * HH + c];
            float w2 = LWhb[(k + 2) * HH + c], w3 = LWhb[(k + 3) * HH + c];
            FMA8X(s_hr, m0, k);
        }
#define PHB_EP(R, A, ZZ)                                                         \
        {                                                                        \
            float e2 = __expf(2.f * (A));                                        \
            float ht = 1.f - 2.f / (e2 + 1.f);                                   \
            float h0v = s_h0[m0 + R][c];                                         \
            float hn = (ZZ) * h0v + (1.f - (ZZ)) * ht;                           \
            int n = nb + m0 + R;                                                 \
            if (!wmask || wmask[n]) hout[(size_t)n * HH + c] = hn;               \
            A = hn;                                                              \
        }
        PHB_EP(0, a0, zz0) PHB_EP(1, a1, zz1) PHB_EP(2, a2, zz2) PHB_EP(3, a3, zz3)
        PHB_EP(4, a4, zz4) PHB_EP(5, a5, zz5) PHB_EP(6, a6, zz6) PHB_EP(7, a7, zz7)
#undef PHB_EP

        if (DOHEAD) {
            __syncthreads();                           // all phase-B s_hr reads done
            s_hr[m0 + 0][c] = a0; s_hr[m0 + 1][c] = a1;
            s_hr[m0 + 2][c] = a2; s_hr[m0 + 3][c] = a3;
            s_hr[m0 + 4][c] = a4; s_hr[m0 + 5][c] = a5;
            s_hr[m0 + 6][c] = a6; s_hr[m0 + 7][c] = a7;
        }
    }

    if (DOHEAD) {
        __syncthreads();
        for (int i = tid; i < 16 * FF; i += 256) {
            int m = i / FF, f = i - m * FF;
            float acc = headb[f];
#pragma unroll 8
            for (int cJ = 0; cJ < HH; cJ++) acc += s_hr[m][cJ] * headW[cJ * FF + f];
            y[(size_t)nb * FF + i] = acc;
        }
    }
}

extern "C" void kernel_launch(void* const* d_in, const int* in_sizes, int n_in,
                              void* d_out, int out_size, void* d_ws, size_t ws_size,
                              hipStream_t stream) {
    const float* x_seq = (const float*)d_in[0];
    const int*   ei    = (const int*)d_in[1];
    const float* ea    = (const float*)d_in[2];
    const unsigned char* mraw = (const unsigned char*)d_in[3];
    const float* Wz  = (const float*)d_in[5];
    const float* Wr  = (const float*)d_in[6];
    const float* Wh  = (const float*)d_in[7];
    const float* bz  = (const float*)d_in[8];
    const float* br  = (const float*)d_in[9];
    const float* bh  = (const float*)d_in[10];
    const float* LWz = (const float*)d_in[11];
    const float* LWr = (const float*)d_in[12];
    const float* LWh = (const float*)d_in[13];
    const float* Lbz = (const float*)d_in[14];
    const float* Lbr = (const float*)d_in[15];
    const float* Lbh = (const float*)d_in[16];
    const float* headW = (const float*)d_in[17];
    const float* headb = (const float*)d_in[18];
    float* out = (float*)d_out;

    // ---- workspace layout. Region A is time-shared: (rank+cnt) die before gathers,
    //      then the same bytes hold xebuf (12 slots batched, 1 slot fallback).
    const size_t sz_rankcnt = sizeof(int) * (size_t)TT * EE + sizeof(int) * TT * NN;
    const size_t sz_xe1  = sizeof(float) * (size_t)NN * FF;
    const size_t sz_xe12 = sz_xe1 * TT;
    const size_t regA_big   = (sz_xe12 > sz_rankcnt) ? sz_xe12 : sz_rankcnt;
    const size_t regA_small = (sz_xe1  > sz_rankcnt) ? sz_xe1  : sz_rankcnt;
    const size_t sz_rest = sizeof(int) * TT * (NN + 1)            // offs
                         + sizeof(int2) * (size_t)TT * EE         // edges
                         + sizeof(float) * TT * NN                // dinv
                         + sizeof(float) * (size_t)NN * HH * 2    // hstore + hp
                         + sizeof(float) * (3 * FF * HH + 3 * HH) // Call + b2
                         + 256 + TT * NN + 1024;                  // mflag + mask + pad
    bool batched = (ws_size >= regA_big + sz_rest);
    size_t regA = batched ? regA_big : regA_small;
    if (!batched && ws_size < regA_small + sz_rest) return;

    char* wp = (char*)d_ws;
    int*   rank   = (int*)wp;
    int*   cnt    = (int*)(wp + sizeof(int) * (size_t)TT * EE);
    float* xebuf  = (float*)wp;                        // aliases rank+cnt (later lifetime)
    wp += regA;
    int*   offs   = (int*)wp;   wp += sizeof(int) * TT * (NN + 1);
    int2*  edges  = (int2*)wp;  wp += sizeof(int2) * (size_t)TT * EE;
    float* dinv   = (float*)wp; wp += sizeof(float) * TT * NN;
    float* hstore = (float*)wp; wp += sizeof(float) * (size_t)NN * HH;
    float* hp     = (float*)wp; wp += sizeof(float) * (size_t)NN * HH;
    float* Call   = (float*)wp; wp += sizeof(float) * 3 * FF * HH;
    float* b2     = (float*)wp; wp += sizeof(float) * 3 * HH;
    int*   mflag  = (int*)wp;   wp += 256;
    unsigned char* mask = (unsigned char*)wp;

    hipMemsetAsync(mflag, 0, sizeof(int), stream);
    k_maskdetect<<<64, 256, 0, stream>>>(mraw, mflag);
    k_maskconv<<<(TT * NN + 255) / 256, 256, 0, stream>>>(mraw, mflag, mask);

    // CSR build + norm coefficients (once for all 12 graphs)
    hipMemsetAsync(cnt, 0, sizeof(int) * TT * NN, stream);
    hipMemsetAsync(hstore, 0, sizeof(float) * NN * HH, stream);
    k_hist<<<(TT * EE + 255) / 256, 256, 0, stream>>>(ei, cnt, rank);
    k_scan<<<TT, 1024, 0, stream>>>(cnt, offs);
    k_fill<<<(TT * EE + 255) / 256, 256, 0, stream>>>(ei, ea, offs, rank, edges);
    k_degdinv<<<(TT * NN + 255) / 256, 256, 0, stream>>>(offs, edges, dinv);
    k_coef<<<(TT * NN + 255) / 256, 256, 0, stream>>>(offs, dinv, edges);
    k_fold<<<3, 128, 0, stream>>>(Wz, Wr, Wh, bz, br, bh, LWz, LWr, LWh, Lbz, Lbr, Lbh, Call, b2);

    const int*  offsl  = offs + (TT - 1) * (NN + 1);
    const int2* edgesl = edges + (size_t)(TT - 1) * EE;
    const float* dil   = dinv + (TT - 1) * NN;

    if (batched) {
        // all 12 encoder gathers (input-only dependent) in ONE launch; rank/cnt are dead now
        k_gather12<<<(TT * NN * 6 + 255) / 256, 256, 0, stream>>>(
            x_seq, offs, edges, dinv, xebuf);

        for (int t = 0; t < TT; t++) {
            const unsigned char* mt = mask + (size_t)t * NN;
            k_cell<0><<<NN / 16, 256, 0, stream>>>(
                xebuf + (size_t)t * NN * FF, hstore, mt, Call, b2, LWz, LWr, LWh, mt, hstore,
                nullptr, nullptr, nullptr);
        }

        // decoder k=0 reuses encoder t=11's gather (identical graph + x)
        for (int k = 0; k < HORZ; k++) {
            const float* xek;
            if (k == 0) {
                xek = xebuf + (size_t)(TT - 1) * NN * FF;
            } else {
                k_gather<<<(NN * 6 + 255) / 256, 256, 0, stream>>>(
                    out + (size_t)(k - 1) * NN * FF, offsl, edgesl, dil, xebuf);
                xek = xebuf;                           // slot 0 free after encoder
            }
            k_cell<1><<<NN / 16, 256, 0, stream>>>(
                xek, (k == 0) ? hstore : hp,
                (k == 0) ? (mask + (size_t)(TT - 1) * NN) : nullptr,
                Call, b2, LWz, LWr, LWh, nullptr, hp,
                headW, headb, out + (size_t)k * NN * FF);
        }
    } else {
        // fallback: R9 sequential path, single xe slot
        for (int t = 0; t < TT; t++) {
            const unsigned char* mt = mask + (size_t)t * NN;
            k_gather<<<(NN * 6 + 255) / 256, 256, 0, stream>>>(
                x_seq + (size_t)t * NN * FF, offs + t * (NN + 1),
                edges + (size_t)t * EE, dinv + t * NN, xebuf);
            k_cell<0><<<NN / 16, 256, 0, stream>>>(
                xebuf, hstore, mt, Call, b2, LWz, LWr, LWh, mt, hstore,
                nullptr, nullptr, nullptr);
        }
        for (int k = 0; k < HORZ; k++) {
            const float* xin = (k == 0) ? (x_seq + (size_t)(TT - 1) * NN * FF)
                                        : (out + (size_t)(k - 1) * NN * FF);
            k_gather<<<(NN * 6 + 255) / 256, 256, 0, stream>>>(
                xin, offsl, edgesl, dil, xebuf);
            k_cell<1><<<NN / 16, 256, 0, stream>>>(
                xebuf, (k == 0) ? hstore : hp,
                (k == 0) ? (mask + (size_t)(TT - 1) * NN) : nullptr,
                Call, b2, LWz, LWr, LWh, nullptr, hp,
                headW, headb, out + (size_t)k * NN * FF);
        }
    }
}

// Round 14
// 4267.291 us; speedup vs baseline: 1.1075x; 1.1075x over previous
//
#include <hip/hip_runtime.h>

#define NN 50000
#define FF 24
#define HH 128
#define TT 12
#define EE 800000
#define HORZ 6

// ---------------- mask dtype detection + canonicalization ----------------

__global__ void k_maskdetect(const unsigned char* __restrict__ m, int* __restrict__ flag) {
    int i = blockIdx.x * 256 + threadIdx.x;
    if (i < 16384 && (i & 3) != 0 && m[i] != 0) atomicOr(flag, 1);
}

__global__ void k_maskconv(const unsigned char* __restrict__ mraw, const int* __restrict__ flag,
                           unsigned char* __restrict__ mout) {
    int i = blockIdx.x * 256 + threadIdx.x;
    if (i >= TT * NN) return;
    if (*flag) mout[i] = (mraw[i] != 0);
    else       mout[i] = (((const int*)mraw)[i] != 0);
}

// ---------------- CSR build: histogram(+rank) -> scan -> rank-based fill ----------------

__global__ void k_hist(const int* __restrict__ ei, int* __restrict__ cnt,
                       int* __restrict__ rank) {
    int idx = blockIdx.x * 256 + threadIdx.x;          // over T*E
    if (idx >= TT * EE) return;
    int t = idx / EE, e = idx - t * EE;
    int dst = ei[((size_t)t * 2 + 1) * EE + e];
    rank[idx] = atomicAdd(&cnt[t * NN + dst], 1);      // rank within dst row
}

__global__ void k_scan(const int* __restrict__ cnt, int* __restrict__ offs) {
    __shared__ int sums[1024];
    int t = blockIdx.x, tid = threadIdx.x;
    const int per = (NN + 1023) / 1024;                // 49
    int base = tid * per;
    int s = 0;
    for (int i = 0; i < per; i++) {
        int idx = base + i;
        if (idx < NN) s += cnt[t * NN + idx];
    }
    sums[tid] = s;
    __syncthreads();
    for (int off = 1; off < 1024; off <<= 1) {
        int tv = (tid >= off) ? sums[tid - off] : 0;
        __syncthreads();
        sums[tid] += tv;
        __syncthreads();
    }
    int run = sums[tid] - s;                           // exclusive prefix
    for (int i = 0; i < per; i++) {
        int idx = base + i;
        if (idx < NN) {
            offs[t * (NN + 1) + idx] = run;
            run += cnt[t * NN + idx];
        }
    }
    if (tid == 1023) offs[t * (NN + 1) + NN] = sums[1023];
}

// atomic-free fill: pos = offs[dst] + rank[e]; interleaved (src,ea) 8B fire-and-forget stores.
__global__ void k_fill(const int* __restrict__ ei, const float* __restrict__ ea,
                       const int* __restrict__ offs, const int* __restrict__ rank,
                       int2* __restrict__ edges) {
    int idx = blockIdx.x * 256 + threadIdx.x;          // over T*E
    if (idx >= TT * EE) return;
    int t = idx / EE, e = idx - t * EE;
    int dst = ei[((size_t)t * 2 + 1) * EE + e];
    int src = ei[((size_t)t * 2 + 0) * EE + e];
    int pos = offs[t * (NN + 1) + dst] + rank[idx];
    edges[(size_t)t * EE + pos] = make_int2(src, __float_as_int(ea[(size_t)t * EE + e]));
}

// deg[n] = sum of incoming ea; dinv = rsqrt(deg+1)
__global__ void k_degdinv(const int* __restrict__ offs, const int2* __restrict__ edges,
                          float* __restrict__ dinv) {
    int idx = blockIdx.x * 256 + threadIdx.x;          // over T*N
    if (idx >= TT * NN) return;
    int t = idx / NN, n = idx - t * NN;
    int b = offs[t * (NN + 1) + n], en = offs[t * (NN + 1) + n + 1];
    float s = 0.f;
    for (int j = b; j < en; j++) s += __int_as_float(edges[(size_t)t * EE + j].y);
    dinv[idx] = rsqrtf(s + 1.0f);
}

// edge coefficient: ea *= dinv[src]*dinv[dst]
__global__ void k_coef(const int* __restrict__ offs, const float* __restrict__ dinv,
                       int2* __restrict__ edges) {
    int idx = blockIdx.x * 256 + threadIdx.x;          // over T*N
    if (idx >= TT * NN) return;
    int t = idx / NN, n = idx - t * NN;
    int b = offs[t * (NN + 1) + n], en = offs[t * (NN + 1) + n + 1];
    float di = dinv[idx];
    for (int j = b; j < en; j++) {
        int2 p = edges[(size_t)t * EE + j];
        float v = __int_as_float(p.y) * di * dinv[t * NN + p.x];
        edges[(size_t)t * EE + j].y = __float_as_int(v);
    }
}

// ---------------- weight folding: Cg = Wg @ LWg[0:H], b2g = bg @ LWg[0:H] + Lbg ----------------

__global__ void k_fold(const float* __restrict__ Wz, const float* __restrict__ Wr,
                       const float* __restrict__ Wh,
                       const float* __restrict__ bz, const float* __restrict__ br,
                       const float* __restrict__ bh,
                       const float* __restrict__ LWz, const float* __restrict__ LWr,
                       const float* __restrict__ LWh,
                       const float* __restrict__ Lbz, const float* __restrict__ Lbr,
                       const float* __restrict__ Lbh,
                       float* __restrict__ Call, float* __restrict__ b2) {
    int g = blockIdx.x, c = threadIdx.x;               // 3 blocks x 128
    const float* W  = g == 0 ? Wz : (g == 1 ? Wr : Wh);
    const float* LW = g == 0 ? LWz : (g == 1 ? LWr : LWh);
    const float* bg = g == 0 ? bz : (g == 1 ? br : bh);
    const float* Lb = g == 0 ? Lbz : (g == 1 ? Lbr : Lbh);
    for (int j = 0; j < FF; j++) {
        float a = 0.f;
        for (int k = 0; k < HH; k++) a += W[j * HH + k] * LW[k * HH + c];
        Call[((size_t)g * FF + j) * HH + c] = a;
    }
    float a = Lb[c];
    for (int k = 0; k < HH; k++) a += bg[k] * LW[k * HH + c];
    b2[g * HH + c] = a;
}

// ---------------- gather body (shared): 6 threads/node, float4 payload, int2 edge meta ----------

__device__ __forceinline__ void gather_body(int n, int q, const float* __restrict__ x,
                                            const int* __restrict__ offs,
                                            const int2* __restrict__ edges,
                                            const float* __restrict__ dinv,
                                            float* __restrict__ xe) {
    int b = offs[n], en = offs[n + 1];
    float di = dinv[n];
    float sc = di * di;
    float4 acc = *(const float4*)&x[(size_t)n * FF + q * 4];
    acc.x *= sc; acc.y *= sc; acc.z *= sc; acc.w *= sc;
    for (int j = b; j < en; j++) {
        int2 p = edges[j];
        float w = __int_as_float(p.y);
        float4 v = *(const float4*)&x[(size_t)p.x * FF + q * 4];
        acc.x += v.x * w; acc.y += v.y * w; acc.z += v.z * w; acc.w += v.w * w;
    }
    *(float4*)&xe[(size_t)n * FF + q * 4] = acc;
}

// per-step gather (decoder / fallback path)
__global__ void k_gather(const float* __restrict__ x, const int* __restrict__ offs,
                         const int2* __restrict__ edges, const float* __restrict__ dinv,
                         float* __restrict__ xe) {
    int idx = blockIdx.x * 256 + threadIdx.x;          // over N*6
    if (idx >= NN * 6) return;
    int n = idx / 6, q = idx - n * 6;
    gather_body(n, q, x, offs, edges, dinv, xe);
}

// batched gather: all 12 encoder steps in one launch (input-dependent only)
__global__ void k_gather12(const float* __restrict__ x_seq, const int* __restrict__ offs_all,
                           const int2* __restrict__ edges_all, const float* __restrict__ dinv_all,
                           float* __restrict__ xe_all) {
    int idx = blockIdx.x * 256 + threadIdx.x;          // over 12*N*6
    if (idx >= TT * NN * 6) return;
    int t = idx / (NN * 6);
    int r = idx - t * (NN * 6);
    int n = r / 6, q = r - n * 6;
    gather_body(n, q,
                x_seq + (size_t)t * NN * FF,
                offs_all + t * (NN + 1),
                edges_all + (size_t)t * EE,
                dinv_all + t * NN,
                xe_all + (size_t)t * NN * FF);
}

// ---------------- fused GRU cell (R9 structure, frozen) ----------------

#define FMA8X2(SARR, M0, K)                                                                  \
    {                                                                                        \
        float4 v_;                                                                           \
        v_ = *(const float4*)&SARR[M0 + 0][K];                                               \
        az0 += v_.x*wz0 + v_.y*wz1 + v_.z*wz2 + v_.w*wz3;                                    \
        ar0 += v_.x*wr0 + v_.y*wr1 + v_.z*wr2 + v_.w*wr3;                                    \
        v_ = *(const float4*)&SARR[M0 + 1][K];                                               \
        az1 += v_.x*wz0 + v_.y*wz1 + v_.z*wz2 + v_.w*wz3;                                    \
        ar1 += v_.x*wr0 + v_.y*wr1 + v_.z*wr2 + v_.w*wr3;                                    \
        v_ = *(const float4*)&SARR[M0 + 2][K];                                               \
        az2 += v_.x*wz0 + v_.y*wz1 + v_.z*wz2 + v_.w*wz3;                                    \
        ar2 += v_.x*wr0 + v_.y*wr1 + v_.z*wr2 + v_.w*wr3;                                    \
        v_ = *(const float4*)&SARR[M0 + 3][K];                                               \
        az3 += v_.x*wz0 + v_.y*wz1 + v_.z*wz2 + v_.w*wz3;                                    \
        ar3 += v_.x*wr0 + v_.y*wr1 + v_.z*wr2 + v_.w*wr3;                                    \
        v_ = *(const float4*)&SARR[M0 + 4][K];                                               \
        az4 += v_.x*wz0 + v_.y*wz1 + v_.z*wz2 + v_.w*wz3;                                    \
        ar4 += v_.x*wr0 + v_.y*wr1 + v_.z*wr2 + v_.w*wr3;                                    \
        v_ = *(const float4*)&SARR[M0 + 5][K];                                               \
        az5 += v_.x*wz0 + v_.y*wz1 + v_.z*wz2 + v_.w*wz3;                                    \
        ar5 += v_.x*wr0 + v_.y*wr1 + v_.z*wr2 + v_.w*wr3;                                    \
        v_ = *(const float4*)&SARR[M0 + 6][K];                                               \
        az6 += v_.x*wz0 + v_.y*wz1 + v_.z*wz2 + v_.w*wz3;                                    \
        ar6 += v_.x*wr0 + v_.y*wr1 + v_.z*wr2 + v_.w*wr3;                                    \
        v_ = *(const float4*)&SARR[M0 + 7][K];                                               \
        az7 += v_.x*wz0 + v_.y*wz1 + v_.z*wz2 + v_.w*wz3;                                    \
        ar7 += v_.x*wr0 + v_.y*wr1 + v_.z*wr2 + v_.w*wr3;                                    \
    }

#define FMA8X(SARR, M0, K)                                                        \
    {                                                                             \
        float4 v_;                                                                \
        v_ = *(const float4*)&SARR[M0 + 0][K]; a0 += v_.x*w0 + v_.y*w1 + v_.z*w2 + v_.w*w3; \
        v_ = *(const float4*)&SARR[M0 + 1][K]; a1 += v_.x*w0 + v_.y*w1 + v_.z*w2 + v_.w*w3; \
        v_ = *(const float4*)&SARR[M0 + 2][K]; a2 += v_.x*w0 + v_.y*w1 + v_.z*w2 + v_.w*w3; \
        v_ = *(const float4*)&SARR[M0 + 3][K]; a3 += v_.x*w0 + v_.y*w1 + v_.z*w2 + v_.w*w3; \
        v_ = *(const float4*)&SARR[M0 + 4][K]; a4 += v_.x*w0 + v_.y*w1 + v_.z*w2 + v_.w*w3; \
        v_ = *(const float4*)&SARR[M0 + 5][K]; a5 += v_.x*w0 + v_.y*w1 + v_.z*w2 + v_.w*w3; \
        v_ = *(const float4*)&SARR[M0 + 6][K]; a6 += v_.x*w0 + v_.y*w1 + v_.z*w2 + v_.w*w3; \
        v_ = *(const float4*)&SARR[M0 + 7][K]; a7 += v_.x*w0 + v_.y*w1 + v_.z*w2 + v_.w*w3; \
    }

template <int DOHEAD>
__global__ __launch_bounds__(256) void k_cell(
        const float* __restrict__ xe, const float* __restrict__ hin,
        const unsigned char* __restrict__ gmask,
        const float* __restrict__ Call, const float* __restrict__ b2,
        const float* __restrict__ LWz, const float* __restrict__ LWr,
        const float* __restrict__ LWh,
        const unsigned char* __restrict__ wmask, float* __restrict__ hout,
        const float* __restrict__ headW, const float* __restrict__ headb,
        float* __restrict__ y) {
    __shared__ float s_xe[16][FF];
    __shared__ float s_h0[16][HH];
    __shared__ float s_z[16][HH];
    __shared__ float s_hr[16][HH];
    int nb = blockIdx.x * 16;
    int tid = threadIdx.x;

    for (int i = tid; i < 16 * FF; i += 256) {
        s_xe[i / FF][i % FF] = xe[(size_t)nb * FF + i];
    }
    for (int i = tid; i < 16 * HH; i += 256) {
        int m = i >> 7, k = i & 127;
        float v = hin[((size_t)nb + m) * HH + k];
        if (gmask && !gmask[nb + m]) v = 0.f;
        s_h0[m][k] = v;
    }
    __syncthreads();

    int g = tid >> 7, c = tid & 127;
    int m0 = g * 8;                                    // row half owned by this thread

    // ---- phase A: z AND r for 8 rows x column c ----
    {
        const float* Cz   = Call;
        const float* Cr   = Call + (size_t)FF * HH;
        const float* LWzb = LWz + (size_t)HH * HH;
        const float* LWrb = LWr + (size_t)HH * HH;
        float bbz = b2[c], bbr = b2[HH + c];
        float az0 = bbz, az1 = bbz, az2 = bbz, az3 = bbz, az4 = bbz, az5 = bbz, az6 = bbz, az7 = bbz;
        float ar0 = bbr, ar1 = bbr, ar2 = bbr, ar3 = bbr, ar4 = bbr, ar5 = bbr, ar6 = bbr, ar7 = bbr;
#pragma unroll
        for (int k = 0; k < FF; k += 4) {
            float wz0 = Cz[(k + 0) * HH + c], wz1 = Cz[(k + 1) * HH + c];
            float wz2 = Cz[(k + 2) * HH + c], wz3 = Cz[(k + 3) * HH + c];
            float wr0 = Cr[(k + 0) * HH + c], wr1 = Cr[(k + 1) * HH + c];
            float wr2 = Cr[(k + 2) * HH + c], wr3 = Cr[(k + 3) * HH + c];
            FMA8X2(s_xe, m0, k);
        }
#pragma unroll 4
        for (int k = 0; k < HH; k += 4) {
            float wz0 = LWzb[(k + 0) * HH + c], wz1 = LWzb[(k + 1) * HH + c];
            float wz2 = LWzb[(k + 2) * HH + c], wz3 = LWzb[(k + 3) * HH + c];
            float wr0 = LWrb[(k + 0) * HH + c], wr1 = LWrb[(k + 1) * HH + c];
            float wr2 = LWrb[(k + 2) * HH + c], wr3 = LWrb[(k + 3) * HH + c];
            FMA8X2(s_h0, m0, k);
        }
#pragma unroll
        for (int r = 0; r < 8; r++) {
            float az = (r == 0) ? az0 : (r == 1) ? az1 : (r == 2) ? az2 : (r == 3) ? az3
                     : (r == 4) ? az4 : (r == 5) ? az5 : (r == 6) ? az6 : az7;
            float ar = (r == 0) ? ar0 : (r == 1) ? ar1 : (r == 2) ? ar2 : (r == 3) ? ar3
                     : (r == 4) ? ar4 : (r == 5) ? ar5 : (r == 6) ? ar6 : ar7;
            s_z[m0 + r][c]  = 1.f / (1.f + __expf(-az));
            s_hr[m0 + r][c] = (1.f / (1.f + __expf(-ar))) * s_h0[m0 + r][c];
        }
    }
    __syncthreads();

    // ---- phase B: htil + GRU update; g=0 rows 0-7, g=1 rows 8-15 ----
    {
        const float* Ch   = Call + (size_t)2 * FF * HH;
        const float* LWhb = LWh + (size_t)HH * HH;
        float bb = b2[2 * HH + c];
        float a0 = bb, a1 = bb, a2 = bb, a3 = bb, a4 = bb, a5 = bb, a6 = bb, a7 = bb;
#pragma unroll
        for (int k = 0; k < FF; k += 4) {
            float w0 = Ch[(k + 0) * HH + c], w1 = Ch[(k + 1) * HH + c];
            float w2 = Ch[(k + 2) * HH + c], w3 = Ch[(k + 3) * HH + c];
            FMA8X(s_xe, m0, k);
        }
#pragma unroll 4
        for (int k = 0; k < HH; k += 4) {
            float w0 = LWhb[(k + 0) * HH + c], w1 = LWhb[(k + 1) * HH + c];
            float w2 = LWhb[(k + 2) * HH + c], w3 = LWhb[(k + 3) * HH + c];
            FMA8X(s_hr, m0, k);
        }
#pragma unroll
        for (int r = 0; r < 8; r++) {
            float a = (r == 0) ? a0 : (r == 1) ? a1 : (r == 2) ? a2 : (r == 3) ? a3
                    : (r == 4) ? a4 : (r == 5) ? a5 : (r == 6) ? a6 : a7;
            int m = m0 + r;
            float e2 = __expf(2.f * a);
            float ht = 1.f - 2.f / (e2 + 1.f);
            float z = s_z[m][c];
            float h0v = s_h0[m][c];
            float hn = z * h0v + (1.f - z) * ht;
            int n = nb + m;
            if (wmask) {
                if (wmask[n]) hout[(size_t)n * HH + c] = hn;
            } else {
                hout[(size_t)n * HH + c] = hn;
            }
            if (DOHEAD) s_z[m][c] = hn;
        }
    }

    if (DOHEAD) {
        __syncthreads();
        for (int i = tid; i < 16 * FF; i += 256) {
            int m = i / FF, f = i - m * FF;
            float acc = headb[f];
#pragma unroll 8
            for (int cJ = 0; cJ < HH; cJ++) acc += s_z[m][cJ] * headW[cJ * FF + f];
            y[(size_t)nb * FF + i] = acc;
        }
    }
}

extern "C" void kernel_launch(void* const* d_in, const int* in_sizes, int n_in,
                              void* d_out, int out_size, void* d_ws, size_t ws_size,
                              hipStream_t stream) {
    const float* x_seq = (const float*)d_in[0];
    const int*   ei    = (const int*)d_in[1];
    const float* ea    = (const float*)d_in[2];
    const unsigned char* mraw = (const unsigned char*)d_in[3];
    const float* Wz  = (const float*)d_in[5];
    const float* Wr  = (const float*)d_in[6];
    const float* Wh  = (const float*)d_in[7];
    const float* bz  = (const float*)d_in[8];
    const float* br  = (const float*)d_in[9];
    const float* bh  = (const float*)d_in[10];
    const float* LWz = (const float*)d_in[11];
    const float* LWr = (const float*)d_in[12];
    const float* LWh = (const float*)d_in[13];
    const float* Lbz = (const float*)d_in[14];
    const float* Lbr = (const float*)d_in[15];
    const float* Lbh = (const float*)d_in[16];
    const float* headW = (const float*)d_in[17];
    const float* headb = (const float*)d_in[18];
    float* out = (float*)d_out;

    // ---- workspace layout. Region A is time-shared: (rank+cnt) die before gathers,
    //      then the same bytes hold xebuf (12 slots batched, 1 slot fallback).
    const size_t sz_rankcnt = sizeof(int) * (size_t)TT * EE + sizeof(int) * TT * NN;
    const size_t sz_xe1  = sizeof(float) * (size_t)NN * FF;
    const size_t sz_xe12 = sz_xe1 * TT;
    const size_t regA_big   = (sz_xe12 > sz_rankcnt) ? sz_xe12 : sz_rankcnt;
    const size_t regA_small = (sz_xe1  > sz_rankcnt) ? sz_xe1  : sz_rankcnt;
    const size_t sz_rest = sizeof(int) * TT * (NN + 1)            // offs
                         + sizeof(int2) * (size_t)TT * EE         // edges
                         + sizeof(float) * TT * NN                // dinv
                         + sizeof(float) * (size_t)NN * HH * 2    // hstore + hp
                         + sizeof(float) * (3 * FF * HH + 3 * HH) // Call + b2
                         + 256 + TT * NN + 1024;                  // mflag + mask + pad
    bool batched = (ws_size >= regA_big + sz_rest);
    size_t regA = batched ? regA_big : regA_small;
    if (!batched && ws_size < regA_small + sz_rest) return;

    char* wp = (char*)d_ws;
    int*   rank   = (int*)wp;
    int*   cnt    = (int*)(wp + sizeof(int) * (size_t)TT * EE);
    float* xebuf  = (float*)wp;                        // aliases rank+cnt (later lifetime)
    wp += regA;
    int*   offs   = (int*)wp;   wp += sizeof(int) * TT * (NN + 1);
    int2*  edges  = (int2*)wp;  wp += sizeof(int2) * (size_t)TT * EE;
    float* dinv   = (float*)wp; wp += sizeof(float) * TT * NN;
    float* hstore = (float*)wp; wp += sizeof(float) * (size_t)NN * HH;
    float* hp     = (float*)wp; wp += sizeof(float) * (size_t)NN * HH;
    float* Call   = (float*)wp; wp += sizeof(float) * 3 * FF * HH;
    float* b2     = (float*)wp; wp += sizeof(float) * 3 * HH;
    int*   mflag  = (int*)wp;   wp += 256;
    unsigned char* mask = (unsigned char*)wp;

    hipMemsetAsync(mflag, 0, sizeof(int), stream);
    k_maskdetect<<<64, 256, 0, stream>>>(mraw, mflag);
    k_maskconv<<<(TT * NN + 255) / 256, 256, 0, stream>>>(mraw, mflag, mask);

    // CSR build + norm coefficients (once for all 12 graphs)
    hipMemsetAsync(cnt, 0, sizeof(int) * TT * NN, stream);
    hipMemsetAsync(hstore, 0, sizeof(float) * NN * HH, stream);
    k_hist<<<(TT * EE + 255) / 256, 256, 0, stream>>>(ei, cnt, rank);
    k_scan<<<TT, 1024, 0, stream>>>(cnt, offs);
    k_fill<<<(TT * EE + 255) / 256, 256, 0, stream>>>(ei, ea, offs, rank, edges);
    k_degdinv<<<(TT * NN + 255) / 256, 256, 0, stream>>>(offs, edges, dinv);
    k_coef<<<(TT * NN + 255) / 256, 256, 0, stream>>>(offs, dinv, edges);
    k_fold<<<3, 128, 0, stream>>>(Wz, Wr, Wh, bz, br, bh, LWz, LWr, LWh, Lbz, Lbr, Lbh, Call, b2);

    const int*  offsl  = offs + (TT - 1) * (NN + 1);
    const int2* edgesl = edges + (size_t)(TT - 1) * EE;
    const float* dil   = dinv + (TT - 1) * NN;

    if (batched) {
        // all 12 encoder gathers (input-only dependent) in ONE launch; rank/cnt are dead now
        k_gather12<<<(TT * NN * 6 + 255) / 256, 256, 0, stream>>>(
            x_seq, offs, edges, dinv, xebuf);

        for (int t = 0; t < TT; t++) {
            const unsigned char* mt = mask + (size_t)t * NN;
            k_cell<0><<<NN / 16, 256, 0, stream>>>(
                xebuf + (size_t)t * NN * FF, hstore, mt, Call, b2, LWz, LWr, LWh, mt, hstore,
                nullptr, nullptr, nullptr);
        }

        // decoder k=0 reuses encoder t=11's gather (identical graph + x)
        for (int k = 0; k < HORZ; k++) {
            const float* xek;
            if (k == 0) {
                xek = xebuf + (size_t)(TT - 1) * NN * FF;
            } else {
                k_gather<<<(NN * 6 + 255) / 256, 256, 0, stream>>>(
                    out + (size_t)(k - 1) * NN * FF, offsl, edgesl, dil, xebuf);
                xek = xebuf;                           // slot 0 free after encoder
            }
            k_cell<1><<<NN / 16, 256, 0, stream>>>(
                xek, (k == 0) ? hstore : hp,
                (k == 0) ? (mask + (size_t)(TT - 1) * NN) : nullptr,
                Call, b2, LWz, LWr, LWh, nullptr, hp,
                headW, headb, out + (size_t)k * NN * FF);
        }
    } else {
        // fallback: R9 sequential path, single xe slot
        for (int t = 0; t < TT; t++) {
            const unsigned char* mt = mask + (size_t)t * NN;
            k_gather<<<(NN * 6 + 255) / 256, 256, 0, stream>>>(
                x_seq + (size_t)t * NN * FF, offs + t * (NN + 1),
                edges + (size_t)t * EE, dinv + t * NN, xebuf);
            k_cell<0><<<NN / 16, 256, 0, stream>>>(
                xebuf, hstore, mt, Call, b2, LWz, LWr, LWh, mt, hstore,
                nullptr, nullptr, nullptr);
        }
        for (int k = 0; k < HORZ; k++) {
            const float* xin = (k == 0) ? (x_seq + (size_t)(TT - 1) * NN * FF)
                                        : (out + (size_t)(k - 1) * NN * FF);
            k_gather<<<(NN * 6 + 255) / 256, 256, 0, stream>>>(
                xin, offsl, edgesl, dil, xebuf);
            k_cell<1><<<NN / 16, 256, 0, stream>>>(
                xebuf, (k == 0) ? hstore : hp,
                (k == 0) ? (mask + (size_t)(TT - 1) * NN) : nullptr,
                Call, b2, LWz, LWr, LWh, nullptr, hp,
                headW, headb, out + (size_t)k * NN * FF);
        }
    }
}